// Round 4
// baseline (48.173 us; speedup 1.0000x reference)
//
#include <hip/hip_runtime.h>
#include <hip/hip_bf16.h>

#define B_TOTAL 2048
#define IN_SZ   288
#define GH      64
#define E_NUM   8
#define OUT_N   256
#define K_TOT   (E_NUM * IN_SZ)   // 2304

#define WT_BLOCKS (K_TOT / 32)    // 72

typedef __attribute__((ext_vector_type(8))) short bf16x8;
typedef __attribute__((ext_vector_type(4))) float f32x4;

__device__ __forceinline__ float elu_f(float x) {
    return x > 0.0f ? x : (expf(x) - 1.0f);
}
__device__ __forceinline__ ushort f2bf(float f) {
    __hip_bfloat16 h = __float2bfloat16(f);
    return *reinterpret_cast<ushort*>(&h);
}
__device__ __forceinline__ unsigned int pack2(float a, float b) {
    return (unsigned int)f2bf(a) | ((unsigned int)f2bf(b) << 16);
}

// ================= k1: transposes =================
// blocks 0..71: w2 [2304][256] f32 -> w2t [256][2304] bf16 (verbatim r3 mapping)
// block 72: g0t [64][288], g1t [64][64], g2t [16][64] (rows 8-15 zero) bf16
__global__ __launch_bounds__(256) void trans_kernel(
    const float* __restrict__ w2,
    const float* __restrict__ g0_w, const float* __restrict__ g1_w,
    const float* __restrict__ g2_w,
    ushort* __restrict__ w2t, ushort* __restrict__ g0t,
    ushort* __restrict__ g1t, ushort* __restrict__ g2t)
{
    const int t = threadIdx.x;
    if (blockIdx.x < WT_BLOCKS) {
        __shared__ float ts[32][33];
        const int k0 = blockIdx.x * 32;
        for (int og = 0; og < 8; ++og) {
            const int o0 = og * 32;
            __syncthreads();
            #pragma unroll
            for (int idx = t; idx < 1024; idx += 256) {
                int r = idx >> 5, c = idx & 31;
                ts[r][c] = w2[(size_t)(k0 + r) * OUT_N + o0 + c];
            }
            __syncthreads();
            #pragma unroll
            for (int idx = t; idx < 1024; idx += 256) {
                int r = idx >> 5, c = idx & 31;
                w2t[(size_t)(o0 + r) * K_TOT + k0 + c] = f2bf(ts[c][r]);
            }
        }
        return;
    }
    // gate weight transposes (uncoalesced reads; tiny, L2-resident)
    for (int idx = t; idx < 64 * IN_SZ; idx += 256) {     // g0t[o][i] = g0_w[i][o]
        int o = idx / IN_SZ, i = idx - o * IN_SZ;
        g0t[idx] = f2bf(g0_w[i * GH + o]);
    }
    for (int idx = t; idx < 64 * 64; idx += 256) {        // g1t[o][i] = g1_w[i][o]
        int o = idx >> 6, i = idx & 63;
        g1t[idx] = f2bf(g1_w[i * GH + o]);
    }
    for (int idx = t; idx < 16 * 64; idx += 256) {        // g2t, zero-padded rows
        int o = idx >> 6, i = idx & 63;
        g2t[idx] = (o < E_NUM) ? f2bf(g2_w[i * E_NUM + o]) : (ushort)0;
    }
}

// ================= k2: MFMA gate + softmax + zc build =================
// 128 blocks x 256 thr; 16 rows each. Waves duplicate over nt = wid&3.
__global__ __launch_bounds__(256) void gate_mfma_kernel(
    const float* __restrict__ z,
    const ushort* __restrict__ g0t, const ushort* __restrict__ g1t,
    const ushort* __restrict__ g2t,
    const float* __restrict__ g0_b, const float* __restrict__ g1_b,
    const float* __restrict__ g2_b,
    float* __restrict__ coef, ushort* __restrict__ zc)
{
    __shared__ float  z_s[16][292];    // f32, +4 pad (stride 292 % 32 == 4 -> 2-way max)
    __shared__ ushort h0s[16][72];     // bf16, stride 144B
    __shared__ ushort h1s[16][72];
    __shared__ float  logit_s[16][16];
    __shared__ float  c_s[16][8];

    const int t   = threadIdx.x;
    const int wid = t >> 6, l = t & 63;
    const int nt  = wid & 3;
    const int r0  = blockIdx.x * 16;

    // ---- stage z rows (f32) ----
    for (int idx = t; idx < 16 * (IN_SZ / 4); idx += 256) {   // 1152 float4
        int r = idx / (IN_SZ / 4), c4 = idx - r * (IN_SZ / 4);
        *(float4*)&z_s[r][c4 * 4] = ((const float4*)(z + (size_t)r0 * IN_SZ))[idx];
    }
    __syncthreads();

    const int arow = l & 15;
    const int acol = (l >> 4) * 8;

    // ---- layer 0: [16x288] @ g0t^T -> h0 [16x64] ----
    {
        f32x4 acc = {0.f, 0.f, 0.f, 0.f};
        const ushort* bp = g0t + (size_t)(nt * 16 + arow) * IN_SZ + acol;
        #pragma unroll
        for (int kk = 0; kk < 9; ++kk) {
            const float* zp = &z_s[arow][kk * 32 + acol];
            float4 v0 = *(const float4*)zp;
            float4 v1 = *(const float4*)(zp + 4);
            bf16x8 a;
            a[0] = (short)f2bf(v0.x); a[1] = (short)f2bf(v0.y);
            a[2] = (short)f2bf(v0.z); a[3] = (short)f2bf(v0.w);
            a[4] = (short)f2bf(v1.x); a[5] = (short)f2bf(v1.y);
            a[6] = (short)f2bf(v1.z); a[7] = (short)f2bf(v1.w);
            bf16x8 b = *(const bf16x8*)(bp + kk * 32);
            acc = __builtin_amdgcn_mfma_f32_16x16x32_bf16(a, b, acc, 0, 0, 0);
        }
        float bias = g0_b[nt * 16 + arow];
        #pragma unroll
        for (int j = 0; j < 4; ++j) {
            int row = (l >> 4) * 4 + j;
            h0s[row][nt * 16 + arow] = f2bf(elu_f(acc[j] + bias));
        }
    }
    __syncthreads();

    // ---- layer 1: [16x64] @ g1t^T -> h1 [16x64] ----
    {
        f32x4 acc = {0.f, 0.f, 0.f, 0.f};
        const ushort* bp = g1t + (size_t)(nt * 16 + arow) * GH + acol;
        #pragma unroll
        for (int kk = 0; kk < 2; ++kk) {
            bf16x8 a = *(const bf16x8*)&h0s[arow][kk * 32 + acol];
            bf16x8 b = *(const bf16x8*)(bp + kk * 32);
            acc = __builtin_amdgcn_mfma_f32_16x16x32_bf16(a, b, acc, 0, 0, 0);
        }
        float bias = g1_b[nt * 16 + arow];
        #pragma unroll
        for (int j = 0; j < 4; ++j) {
            int row = (l >> 4) * 4 + j;
            h1s[row][nt * 16 + arow] = f2bf(elu_f(acc[j] + bias));
        }
    }
    __syncthreads();

    // ---- layer 2: [16x64] @ g2t^T -> logits [16x8] (cols 8-15 pad) ----
    if (nt == 0) {
        f32x4 acc = {0.f, 0.f, 0.f, 0.f};
        const ushort* bp = g2t + (size_t)arow * GH + acol;
        #pragma unroll
        for (int kk = 0; kk < 2; ++kk) {
            bf16x8 a = *(const bf16x8*)&h1s[arow][kk * 32 + acol];
            bf16x8 b = *(const bf16x8*)(bp + kk * 32);
            acc = __builtin_amdgcn_mfma_f32_16x16x32_bf16(a, b, acc, 0, 0, 0);
        }
        float bias = (arow < E_NUM) ? g2_b[arow] : 0.f;
        #pragma unroll
        for (int j = 0; j < 4; ++j) {
            int row = (l >> 4) * 4 + j;
            logit_s[row][arow] = acc[j] + bias;
        }
    }
    __syncthreads();

    // ---- softmax: t<128 -> (row t>>3, e t&7) ----
    if (t < 128) {
        const int row = t >> 3, e = t & 7;
        float m = logit_s[row][0];
        #pragma unroll
        for (int k = 1; k < E_NUM; ++k) m = fmaxf(m, logit_s[row][k]);
        float s = 0.f;
        #pragma unroll
        for (int k = 0; k < E_NUM; ++k) s += expf(logit_s[row][k] - m);
        float c = expf(logit_s[row][e] - m) / s;
        c_s[row][e] = c;
        coef[(r0 + row) * E_NUM + e] = c;
    }
    __syncthreads();

    // ---- zc[b, e*288+i] = bf16(c_s[b][e] * z_s[b][i]), 16B stores ----
    for (int idx = t; idx < 16 * (K_TOT / 8); idx += 256) {   // 4608 chunks, 18 iters
        int row = idx / (K_TOT / 8);
        int c8  = idx - row * (K_TOT / 8);
        int e   = c8 / 36;                  // 288/8 = 36 chunks per expert
        int i0  = (c8 - e * 36) * 8;
        float c = c_s[row][e];
        const float* zp = &z_s[row][i0];
        float4 v0 = *(const float4*)zp;
        float4 v1 = *(const float4*)(zp + 4);
        int4 q;
        q.x = (int)pack2(c * v0.x, c * v0.y);
        q.y = (int)pack2(c * v0.z, c * v0.w);
        q.z = (int)pack2(c * v1.x, c * v1.y);
        q.w = (int)pack2(c * v1.z, c * v1.w);
        *(int4*)&zc[(size_t)(r0 + row) * K_TOT + c8 * 8] = q;
    }
}

// ================= k3: GEMM (byte-identical to r2/r3) =================
#define BMg 32
#define BNg 64
#define BKg 64
#define LDK 88
#define NKI (K_TOT / BKg) // 36

__global__ __launch_bounds__(256) void gemm_kernel(
    const ushort* __restrict__ zc, const ushort* __restrict__ w2t,
    const float* __restrict__ coef, const float* __restrict__ b2,
    float* __restrict__ out)
{
    __shared__ ushort As[BMg][LDK];
    __shared__ ushort Bs[BNg][LDK];
    __shared__ float  c_s[BMg][E_NUM];

    const int t   = threadIdx.x;
    const int wid = t >> 6, l = t & 63;
    const int m0 = blockIdx.x * BMg;
    const int n0 = blockIdx.y * BNg;

    ((float*)c_s)[t] = coef[m0 * E_NUM + t];

    const int ar = t >> 3;
    const int ac = (t & 7) * 8;
    const ushort* gA  = zc  + (size_t)(m0 + ar) * K_TOT + ac;
    const ushort* gB0 = w2t + (size_t)(n0 + ar) * K_TOT + ac;
    const ushort* gB1 = w2t + (size_t)(n0 + 32 + ar) * K_TOT + ac;

    int4 ra  = *(const int4*)gA;
    int4 rb0 = *(const int4*)gB0;
    int4 rb1 = *(const int4*)gB1;

    const int mt  = wid & 1;
    const int nt0 = (wid >> 1) * 2;

    f32x4 acc0 = {0.f, 0.f, 0.f, 0.f};
    f32x4 acc1 = {0.f, 0.f, 0.f, 0.f};

    const int frow = l & 15, fk = (l >> 4) * 8;
    const ushort* aRd  = &As[mt * 16 + frow][fk];
    const ushort* bRd0 = &Bs[nt0 * 16 + frow][fk];
    const ushort* bRd1 = &Bs[(nt0 + 1) * 16 + frow][fk];

    for (int ki = 0; ki < NKI; ++ki) {
        *(int4*)&As[ar][ac] = ra;
        *(int4*)&Bs[ar][ac] = rb0;
        *(int4*)&Bs[32 + ar][ac] = rb1;
        __syncthreads();
        if (ki + 1 < NKI) {
            gA += BKg; gB0 += BKg; gB1 += BKg;
            ra  = *(const int4*)gA;
            rb0 = *(const int4*)gB0;
            rb1 = *(const int4*)gB1;
        }
        bf16x8 a0  = *(const bf16x8*)aRd;
        bf16x8 a1  = *(const bf16x8*)(aRd + 32);
        bf16x8 b00 = *(const bf16x8*)bRd0;
        bf16x8 b01 = *(const bf16x8*)(bRd0 + 32);
        bf16x8 b10 = *(const bf16x8*)bRd1;
        bf16x8 b11 = *(const bf16x8*)(bRd1 + 32);
        acc0 = __builtin_amdgcn_mfma_f32_16x16x32_bf16(a0, b00, acc0, 0, 0, 0);
        acc1 = __builtin_amdgcn_mfma_f32_16x16x32_bf16(a0, b10, acc1, 0, 0, 0);
        acc0 = __builtin_amdgcn_mfma_f32_16x16x32_bf16(a1, b01, acc0, 0, 0, 0);
        acc1 = __builtin_amdgcn_mfma_f32_16x16x32_bf16(a1, b11, acc1, 0, 0, 0);
        __syncthreads();
    }

    const int col0 = n0 + nt0 * 16 + frow;
    const int col1 = col0 + 16;
    #pragma unroll
    for (int j = 0; j < 4; ++j) {
        int rloc = mt * 16 + (l >> 4) * 4 + j;
        int row = m0 + rloc;
        float bias0 = 0.f, bias1 = 0.f;
        #pragma unroll
        for (int e = 0; e < E_NUM; ++e) {
            float c = c_s[rloc][e];
            bias0 = fmaf(c, b2[e * OUT_N + col0], bias0);
            bias1 = fmaf(c, b2[e * OUT_N + col1], bias1);
        }
        out[(size_t)row * OUT_N + col0] = acc0[j] + bias0;
        out[(size_t)row * OUT_N + col1] = acc1[j] + bias1;
    }
}

// ================= fallback: f32 gate + direct (small ws only) =================
__global__ __launch_bounds__(64) void gate_fb_kernel(
    const float* __restrict__ z,
    const float* __restrict__ g0_w, const float* __restrict__ g0_b,
    const float* __restrict__ g1_w, const float* __restrict__ g1_b,
    const float* __restrict__ g2_w, const float* __restrict__ g2_b,
    float* __restrict__ coef)
{
    __shared__ float z_s[IN_SZ];
    __shared__ float h0_s[GH];
    __shared__ float h1_s[GH];
    const int b = blockIdx.x;
    const int t = threadIdx.x;
    const float* zr = z + (size_t)b * IN_SZ;
    for (int i = t; i < IN_SZ; i += 64) z_s[i] = zr[i];
    __syncthreads();
    float a0 = g0_b[t];
    for (int i = 0; i < IN_SZ; ++i) a0 = fmaf(z_s[i], g0_w[i * GH + t], a0);
    h0_s[t] = elu_f(a0);
    __syncthreads();
    float a1 = g1_b[t];
    for (int k = 0; k < GH; ++k) a1 = fmaf(h0_s[k], g1_w[k * GH + t], a1);
    h1_s[t] = elu_f(a1);
    __syncthreads();
    if (t < E_NUM) {
        float lg = g2_b[t];
        for (int k = 0; k < GH; ++k) lg = fmaf(h1_s[k], g2_w[k * E_NUM + t], lg);
        float m = lg;
        for (int d = 1; d < 8; d <<= 1) m = fmaxf(m, __shfl_xor(m, d, 8));
        float ex = expf(lg - m);
        float s = ex;
        for (int d = 1; d < 8; d <<= 1) s += __shfl_xor(s, d, 8);
        coef[b * E_NUM + t] = ex / s;
    }
}

__global__ __launch_bounds__(256) void direct_kernel(
    const float* __restrict__ z, const float* __restrict__ w2,
    const float* __restrict__ b2, const float* __restrict__ coef,
    float* __restrict__ out)
{
    __shared__ float z_s[8][IN_SZ];
    __shared__ float c_s[8][E_NUM];
    const int b0 = blockIdx.x * 8;
    const int t  = threadIdx.x;
    for (int idx = t; idx < 8 * IN_SZ; idx += 256)
        ((float*)z_s)[idx] = z[(size_t)b0 * IN_SZ + idx];
    if (t < 64) c_s[t >> 3][t & 7] = coef[b0 * E_NUM + t];
    __syncthreads();
    float outv[8];
    #pragma unroll
    for (int r = 0; r < 8; ++r) outv[r] = 0.0f;
    for (int e = 0; e < E_NUM; ++e) {
        const float* w = w2 + (size_t)e * IN_SZ * OUT_N + t;
        float tmp[8];
        #pragma unroll
        for (int r = 0; r < 8; ++r) tmp[r] = 0.0f;
        #pragma unroll 4
        for (int i = 0; i < IN_SZ; ++i) {
            float wv = w[i * OUT_N];
            #pragma unroll
            for (int r = 0; r < 8; ++r) tmp[r] += z_s[r][i] * wv;
        }
        float bv = b2[e * OUT_N + t];
        #pragma unroll
        for (int r = 0; r < 8; ++r) outv[r] += c_s[r][e] * (tmp[r] + bv);
    }
    #pragma unroll
    for (int r = 0; r < 8; ++r) out[(size_t)(b0 + r) * OUT_N + t] = outv[r];
}

extern "C" void kernel_launch(void* const* d_in, const int* in_sizes, int n_in,
                              void* d_out, int out_size, void* d_ws, size_t ws_size,
                              hipStream_t stream) {
    const float* z    = (const float*)d_in[0];
    const float* g0_w = (const float*)d_in[1];
    const float* g0_b = (const float*)d_in[2];
    const float* g1_w = (const float*)d_in[3];
    const float* g1_b = (const float*)d_in[4];
    const float* g2_w = (const float*)d_in[5];
    const float* g2_b = (const float*)d_in[6];
    // d_in[7..10] = w0,b0,w1,b1 are dead in the reference
    const float* w2   = (const float*)d_in[11];
    const float* b2   = (const float*)d_in[12];
    float* out = (float*)d_out;

    const size_t coef_b = (size_t)B_TOTAL * E_NUM * sizeof(float);     // 65,536
    const size_t zc_b   = (size_t)B_TOTAL * K_TOT * sizeof(ushort);    // 9,437,184
    const size_t w2t_b  = (size_t)OUT_N * K_TOT * sizeof(ushort);      // 1,179,648
    const size_t g0t_b  = (size_t)64 * IN_SZ * sizeof(ushort);         // 36,864
    const size_t g1t_b  = (size_t)64 * 64 * sizeof(ushort);            // 8,192
    const size_t g2t_b  = (size_t)16 * 64 * sizeof(ushort);            // 2,048
    const size_t need   = coef_b + zc_b + w2t_b + g0t_b + g1t_b + g2t_b;

    char* p = (char*)d_ws;
    float*  coef = (float*)p;                    p += coef_b;
    ushort* zc   = (ushort*)p;                   p += zc_b;
    ushort* w2t  = (ushort*)p;                   p += w2t_b;
    ushort* g0t  = (ushort*)p;                   p += g0t_b;
    ushort* g1t  = (ushort*)p;                   p += g1t_b;
    ushort* g2t  = (ushort*)p;

    if (ws_size >= need) {
        trans_kernel<<<WT_BLOCKS + 1, 256, 0, stream>>>(w2, g0_w, g1_w, g2_w,
                                                        w2t, g0t, g1t, g2t);
        gate_mfma_kernel<<<B_TOTAL / 16, 256, 0, stream>>>(
            z, g0t, g1t, g2t, g0_b, g1_b, g2_b, coef, zc);
        gemm_kernel<<<dim3(B_TOTAL / BMg, OUT_N / BNg), 256, 0, stream>>>(
            zc, w2t, coef, b2, out);
    } else {
        gate_fb_kernel<<<B_TOTAL, 64, 0, stream>>>(z, g0_w, g0_b, g1_w, g1_b,
                                                   g2_w, g2_b, coef);
        direct_kernel<<<B_TOTAL / 8, 256, 0, stream>>>(z, w2, b2, coef, out);
    }
}

// Round 5
// 37.712 us; speedup vs baseline: 1.2774x; 1.2774x over previous
//
#include <hip/hip_runtime.h>
#include <hip/hip_bf16.h>

#define B_TOTAL 2048
#define IN_SZ   288
#define GH      64
#define E_NUM   8
#define OUT_N   256
#define K_TOT   (E_NUM * IN_SZ)   // 2304

#define WT2_BLOCKS  576           // 72 k-slabs x 8 o-slabs
#define GATE_BLOCKS 128           // 16 rows each

typedef __attribute__((ext_vector_type(8))) short bf16x8;
typedef __attribute__((ext_vector_type(4))) float f32x4;

__device__ __forceinline__ float elu_f(float x) {
    return x > 0.0f ? x : (expf(x) - 1.0f);
}
__device__ __forceinline__ ushort f2bf(float f) {
    __hip_bfloat16 h = __float2bfloat16(f);
    return *reinterpret_cast<ushort*>(&h);
}

// ================= k1: fused prep =================
// blocks [0,576): w2 [2304][256] f32 -> w2t [256][2304] bf16, one 32x32 tile each
// blocks [576,704): MFMA gate for 16 rows -> coef (gate wts transposed into LDS per block)
__global__ __launch_bounds__(256) void prep_kernel(
    const float* __restrict__ w2, const float* __restrict__ z,
    const float* __restrict__ g0_w, const float* __restrict__ g0_b,
    const float* __restrict__ g1_w, const float* __restrict__ g1_b,
    const float* __restrict__ g2_w, const float* __restrict__ g2_b,
    ushort* __restrict__ w2t, float* __restrict__ coef)
{
    __shared__ char smem[64000];
    const int t = threadIdx.x;

    if (blockIdx.x < WT2_BLOCKS) {
        float (*ts)[33] = (float(*)[33])smem;
        const int k0 = (blockIdx.x >> 3) * 32;
        const int o0 = (blockIdx.x & 7) * 32;
        #pragma unroll
        for (int idx = t; idx < 1024; idx += 256) {
            int r = idx >> 5, c = idx & 31;
            ts[r][c] = w2[(size_t)(k0 + r) * OUT_N + o0 + c];
        }
        __syncthreads();
        #pragma unroll
        for (int idx = t; idx < 1024; idx += 256) {
            int r = idx >> 5, c = idx & 31;   // r = o-off, c = k-off
            w2t[(size_t)(o0 + r) * K_TOT + k0 + c] = f2bf(ts[c][r]);
        }
        return;
    }

    // ---- gate block LDS carve (64000 B total) ----
    ushort* w0s = (ushort*)smem;               // [64][296] bf16  37888
    ushort* w1s = (ushort*)(smem + 37888);     // [64][72]         9216
    ushort* w2s = (ushort*)(smem + 47104);     // [16][72]         2304
    ushort* zbs = (ushort*)(smem + 49408);     // [16][296]        9472
    ushort* h0s = (ushort*)(smem + 58880);     // [16][72]         2304
    ushort* h1s = (ushort*)(smem + 61184);     // [16][72]         2304
    float*  lgs = (float*)(smem + 63488);      // [16][8]           512

    const int r0 = (blockIdx.x - WT2_BLOCKS) * 16;

    // stage gate weights transposed (coalesced global reads, LDS scatter)
    for (int idx = t; idx < 288 * 64; idx += 256) {   // g0_w[i][o] -> w0s[o][i]
        int i = idx >> 6, o = idx & 63;
        w0s[o * 296 + i] = f2bf(g0_w[idx]);
    }
    for (int idx = t; idx < 64 * 64; idx += 256) {    // g1_w[i][o] -> w1s[o][i]
        int i = idx >> 6, o = idx & 63;
        w1s[o * 72 + i] = f2bf(g1_w[idx]);
    }
    for (int idx = t; idx < 64 * 8; idx += 256) {     // g2_w[i][o] -> w2s[o][i]
        int i = idx >> 3, o = idx & 7;
        w2s[o * 72 + i] = f2bf(g2_w[idx]);
    }
    for (int idx = t; idx < 8 * 72; idx += 256) w2s[576 + idx] = 0;   // pad rows 8-15
    // stage z rows as bf16
    for (int idx = t; idx < 1152; idx += 256) {       // 16 rows x 72 float4
        int r = idx / 72, c4 = idx - r * 72;
        float4 v = *(const float4*)(z + (size_t)(r0 + r) * IN_SZ + c4 * 4);
        ushort4 o4;
        o4.x = f2bf(v.x); o4.y = f2bf(v.y); o4.z = f2bf(v.z); o4.w = f2bf(v.w);
        *(ushort4*)&zbs[r * 296 + c4 * 4] = o4;
    }
    __syncthreads();

    const int wid = t >> 6, l = t & 63;
    const int nt = wid;                   // wave -> 16-col tile
    const int arow = l & 15, acol = (l >> 4) * 8;

    // layer 0: [16x288] @ w0s^T -> h0 [16x64]
    {
        f32x4 acc = {0.f, 0.f, 0.f, 0.f};
        #pragma unroll
        for (int kk = 0; kk < 9; ++kk) {
            bf16x8 a = *(const bf16x8*)&zbs[arow * 296 + kk * 32 + acol];
            bf16x8 b = *(const bf16x8*)&w0s[(nt * 16 + arow) * 296 + kk * 32 + acol];
            acc = __builtin_amdgcn_mfma_f32_16x16x32_bf16(a, b, acc, 0, 0, 0);
        }
        float bias = g0_b[nt * 16 + arow];
        #pragma unroll
        for (int j = 0; j < 4; ++j)
            h0s[((l >> 4) * 4 + j) * 72 + nt * 16 + arow] = f2bf(elu_f(acc[j] + bias));
    }
    __syncthreads();

    // layer 1: [16x64] @ w1s^T -> h1 [16x64]
    {
        f32x4 acc = {0.f, 0.f, 0.f, 0.f};
        #pragma unroll
        for (int kk = 0; kk < 2; ++kk) {
            bf16x8 a = *(const bf16x8*)&h0s[arow * 72 + kk * 32 + acol];
            bf16x8 b = *(const bf16x8*)&w1s[(nt * 16 + arow) * 72 + kk * 32 + acol];
            acc = __builtin_amdgcn_mfma_f32_16x16x32_bf16(a, b, acc, 0, 0, 0);
        }
        float bias = g1_b[nt * 16 + arow];
        #pragma unroll
        for (int j = 0; j < 4; ++j)
            h1s[((l >> 4) * 4 + j) * 72 + nt * 16 + arow] = f2bf(elu_f(acc[j] + bias));
    }
    __syncthreads();

    // layer 2: [16x64] @ w2s^T -> logits [16x8]
    if (nt == 0) {
        f32x4 acc = {0.f, 0.f, 0.f, 0.f};
        #pragma unroll
        for (int kk = 0; kk < 2; ++kk) {
            bf16x8 a = *(const bf16x8*)&h1s[arow * 72 + kk * 32 + acol];
            bf16x8 b = *(const bf16x8*)&w2s[arow * 72 + kk * 32 + acol];
            acc = __builtin_amdgcn_mfma_f32_16x16x32_bf16(a, b, acc, 0, 0, 0);
        }
        if (arow < E_NUM) {
            float bias = g2_b[arow];
            #pragma unroll
            for (int j = 0; j < 4; ++j)
                lgs[((l >> 4) * 4 + j) * 8 + arow] = acc[j] + bias;
        }
    }
    __syncthreads();

    // softmax: t<128 -> (row t>>3, expert t&7)
    if (t < 128) {
        const int row = t >> 3, e = t & 7;
        float m = lgs[row * 8 + 0];
        #pragma unroll
        for (int k = 1; k < E_NUM; ++k) m = fmaxf(m, lgs[row * 8 + k]);
        float s = 0.f;
        #pragma unroll
        for (int k = 0; k < E_NUM; ++k) s += expf(lgs[row * 8 + k] - m);
        coef[(r0 + row) * E_NUM + e] = expf(lgs[row * 8 + e] - m) / s;
    }
}

// ================= k2: barrier-free direct GEMM =================
// grid (32, 8): 64 rows x 32 cols per block; wave = 16 rows x 32 cols.
// A (z rows, bf16) in registers, reused across all 8 experts;
// B fragments loaded direct from L2-resident w2t; per-expert acc scaling by coef.
__global__ __launch_bounds__(256, 1) void gemm_direct(
    const float* __restrict__ z, const ushort* __restrict__ w2t,
    const float* __restrict__ coef, const float* __restrict__ b2,
    float* __restrict__ out)
{
    const int t = threadIdx.x, wid = t >> 6, l = t & 63;
    const int frow = l & 15, fk = (l >> 4) * 8;
    const int mbase = blockIdx.x * 64 + wid * 16;
    const int n0 = blockIdx.y * 32;

    // A fragments: z row (mbase+frow), K=288, bf16
    bf16x8 A[9];
    {
        const float* zr = z + (size_t)(mbase + frow) * IN_SZ + fk;
        #pragma unroll
        for (int kk = 0; kk < 9; ++kk) {
            float4 v0 = *(const float4*)(zr + kk * 32);
            float4 v1 = *(const float4*)(zr + kk * 32 + 4);
            bf16x8 a;
            a[0] = (short)f2bf(v0.x); a[1] = (short)f2bf(v0.y);
            a[2] = (short)f2bf(v0.z); a[3] = (short)f2bf(v0.w);
            a[4] = (short)f2bf(v1.x); a[5] = (short)f2bf(v1.y);
            a[6] = (short)f2bf(v1.z); a[7] = (short)f2bf(v1.w);
            A[kk] = a;
        }
    }

    // coef for this lane's 4 C-rows
    float cf[4][E_NUM];
    #pragma unroll
    for (int j = 0; j < 4; ++j) {
        const float4* cp = (const float4*)(coef + (size_t)(mbase + (l >> 4) * 4 + j) * E_NUM);
        float4 c0 = cp[0], c1 = cp[1];
        cf[j][0] = c0.x; cf[j][1] = c0.y; cf[j][2] = c0.z; cf[j][3] = c0.w;
        cf[j][4] = c1.x; cf[j][5] = c1.y; cf[j][6] = c1.z; cf[j][7] = c1.w;
    }

    f32x4 acc0 = {0.f, 0.f, 0.f, 0.f};
    f32x4 acc1 = {0.f, 0.f, 0.f, 0.f};
    const ushort* B0 = w2t + (size_t)(n0 + frow) * K_TOT + fk;
    const ushort* B1 = w2t + (size_t)(n0 + 16 + frow) * K_TOT + fk;

    #pragma unroll 2
    for (int e = 0; e < E_NUM; ++e) {
        f32x4 p0 = {0.f, 0.f, 0.f, 0.f};
        f32x4 p1 = {0.f, 0.f, 0.f, 0.f};
        #pragma unroll
        for (int kk = 0; kk < 9; ++kk) {
            bf16x8 b0 = *(const bf16x8*)(B0 + e * IN_SZ + kk * 32);
            bf16x8 b1 = *(const bf16x8*)(B1 + e * IN_SZ + kk * 32);
            p0 = __builtin_amdgcn_mfma_f32_16x16x32_bf16(A[kk], b0, p0, 0, 0, 0);
            p1 = __builtin_amdgcn_mfma_f32_16x16x32_bf16(A[kk], b1, p1, 0, 0, 0);
        }
        #pragma unroll
        for (int j = 0; j < 4; ++j) {
            acc0[j] = fmaf(cf[j][e], p0[j], acc0[j]);
            acc1[j] = fmaf(cf[j][e], p1[j], acc1[j]);
        }
    }

    // epilogue: mixed bias + store
    const int col0 = n0 + frow, col1 = n0 + 16 + frow;
    #pragma unroll
    for (int j = 0; j < 4; ++j) {
        const int row = mbase + (l >> 4) * 4 + j;
        float b0v = 0.f, b1v = 0.f;
        #pragma unroll
        for (int e = 0; e < E_NUM; ++e) {
            b0v = fmaf(cf[j][e], b2[e * OUT_N + col0], b0v);
            b1v = fmaf(cf[j][e], b2[e * OUT_N + col1], b1v);
        }
        out[(size_t)row * OUT_N + col0] = acc0[j] + b0v;
        out[(size_t)row * OUT_N + col1] = acc1[j] + b1v;
    }
}

// ================= fallback (small ws): f32 gate + direct =================
__global__ __launch_bounds__(64) void gate_fb_kernel(
    const float* __restrict__ z,
    const float* __restrict__ g0_w, const float* __restrict__ g0_b,
    const float* __restrict__ g1_w, const float* __restrict__ g1_b,
    const float* __restrict__ g2_w, const float* __restrict__ g2_b,
    float* __restrict__ coef)
{
    __shared__ float z_s[IN_SZ];
    __shared__ float h0_s[GH];
    __shared__ float h1_s[GH];
    const int b = blockIdx.x;
    const int t = threadIdx.x;
    const float* zr = z + (size_t)b * IN_SZ;
    for (int i = t; i < IN_SZ; i += 64) z_s[i] = zr[i];
    __syncthreads();
    float a0 = g0_b[t];
    for (int i = 0; i < IN_SZ; ++i) a0 = fmaf(z_s[i], g0_w[i * GH + t], a0);
    h0_s[t] = elu_f(a0);
    __syncthreads();
    float a1 = g1_b[t];
    for (int k = 0; k < GH; ++k) a1 = fmaf(h0_s[k], g1_w[k * GH + t], a1);
    h1_s[t] = elu_f(a1);
    __syncthreads();
    if (t < E_NUM) {
        float lg = g2_b[t];
        for (int k = 0; k < GH; ++k) lg = fmaf(h1_s[k], g2_w[k * E_NUM + t], lg);
        float m = lg;
        for (int d = 1; d < 8; d <<= 1) m = fmaxf(m, __shfl_xor(m, d, 8));
        float ex = expf(lg - m);
        float s = ex;
        for (int d = 1; d < 8; d <<= 1) s += __shfl_xor(s, d, 8);
        coef[b * E_NUM + t] = ex / s;
    }
}

__global__ __launch_bounds__(256) void direct_kernel(
    const float* __restrict__ z, const float* __restrict__ w2,
    const float* __restrict__ b2, const float* __restrict__ coef,
    float* __restrict__ out)
{
    __shared__ float z_s[8][IN_SZ];
    __shared__ float c_s[8][E_NUM];
    const int b0 = blockIdx.x * 8;
    const int t  = threadIdx.x;
    for (int idx = t; idx < 8 * IN_SZ; idx += 256)
        ((float*)z_s)[idx] = z[(size_t)b0 * IN_SZ + idx];
    if (t < 64) c_s[t >> 3][t & 7] = coef[b0 * E_NUM + t];
    __syncthreads();
    float outv[8];
    #pragma unroll
    for (int r = 0; r < 8; ++r) outv[r] = 0.0f;
    for (int e = 0; e < E_NUM; ++e) {
        const float* w = w2 + (size_t)e * IN_SZ * OUT_N + t;
        float tmp[8];
        #pragma unroll
        for (int r = 0; r < 8; ++r) tmp[r] = 0.0f;
        #pragma unroll 4
        for (int i = 0; i < IN_SZ; ++i) {
            float wv = w[i * OUT_N];
            #pragma unroll
            for (int r = 0; r < 8; ++r) tmp[r] += z_s[r][i] * wv;
        }
        float bv = b2[e * OUT_N + t];
        #pragma unroll
        for (int r = 0; r < 8; ++r) outv[r] += c_s[r][e] * (tmp[r] + bv);
    }
    #pragma unroll
    for (int r = 0; r < 8; ++r) out[(size_t)(b0 + r) * OUT_N + t] = outv[r];
}

extern "C" void kernel_launch(void* const* d_in, const int* in_sizes, int n_in,
                              void* d_out, int out_size, void* d_ws, size_t ws_size,
                              hipStream_t stream) {
    const float* z    = (const float*)d_in[0];
    const float* g0_w = (const float*)d_in[1];
    const float* g0_b = (const float*)d_in[2];
    const float* g1_w = (const float*)d_in[3];
    const float* g1_b = (const float*)d_in[4];
    const float* g2_w = (const float*)d_in[5];
    const float* g2_b = (const float*)d_in[6];
    // d_in[7..10] = w0,b0,w1,b1 are dead in the reference (layer_out never fed back)
    const float* w2   = (const float*)d_in[11];
    const float* b2   = (const float*)d_in[12];
    float* out = (float*)d_out;

    const size_t coef_b = (size_t)B_TOTAL * E_NUM * sizeof(float);     // 64 KB
    const size_t w2t_b  = (size_t)OUT_N * K_TOT * sizeof(ushort);      // 1.18 MB

    float*  coef = (float*)d_ws;
    ushort* w2t  = (ushort*)((char*)d_ws + coef_b);

    if (ws_size >= coef_b + w2t_b) {
        prep_kernel<<<WT2_BLOCKS + GATE_BLOCKS, 256, 0, stream>>>(
            w2, z, g0_w, g0_b, g1_w, g1_b, g2_w, g2_b, w2t, coef);
        gemm_direct<<<dim3(B_TOTAL / 64, OUT_N / 32), 256, 0, stream>>>(
            z, w2t, coef, b2, out);
    } else {
        gate_fb_kernel<<<B_TOTAL, 64, 0, stream>>>(z, g0_w, g0_b, g1_w, g1_b,
                                                   g2_w, g2_b, coef);
        direct_kernel<<<B_TOTAL / 8, 256, 0, stream>>>(z, w2, b2, coef, out);
    }
}